// Round 3
// baseline (2165.779 us; speedup 1.0000x reference)
//
#include <hip/hip_runtime.h>
#include <hip/hip_bf16.h>
#include <math.h>

constexpr int NN = 100000;
constexpr int EE = 1000000;
constexpr int RRR = 3;
constexpr int DIN = 128;
constexpr int DOUT = 64;
constexpr float SLOPE = 0.2f;
constexpr int NR = RRR * NN;                 // 300000 segments (relation-major)
constexpr int BSEG = 256;                    // segments per bucket
constexpr int NBUCK = (NR + BSEG - 1) / BSEG;   // 1172
constexpr int BCAP = 4096;                   // max edges/bucket (mean 2560, sigma ~51)

// ---------------- GEMM + attention logits ----------------
// h[r] = x @ W[r]; als[r][n] = h[r][n]·a_src[r]; ald[r][n] = h[r][n]·a_dst[r]
template<int INP>
__global__ __launch_bounds__(256) void gemm_att(
    const float* __restrict__ x,     // [NN, INP]
    const float* __restrict__ W,     // [R, INP, 64]
    const float* __restrict__ asrc,  // [R, 64]
    const float* __restrict__ adst,  // [R, 64]
    float* __restrict__ h,           // [R, NN, 64]
    float* __restrict__ als,         // [R, NN]
    float* __restrict__ ald)         // [R, NN]
{
    constexpr int WS = INP + 4;           // stride 132/68 floats: conflict-free b128
    __shared__ float Wt[64 * WS];         // W transposed: Wt[col][k]
    __shared__ float xs[32 * INP];        // 32 x-rows
    const int r = blockIdx.y;
    const int row0 = blockIdx.x * 32;     // NN/32 = 3125 exact
    const int t = threadIdx.x;
    const int lane = t & 63;
    const int warp = t >> 6;

    const float* Wr = W + r * (INP * DOUT);
    for (int idx = t; idx < INP * DOUT; idx += 256) {
        int k = idx >> 6, c = idx & 63;
        Wt[c * WS + k] = Wr[idx];
    }
    const float4* xg = (const float4*)(x + (size_t)row0 * INP);
    float4* xs4 = (float4*)xs;
    for (int i = t; i < 32 * INP / 4; i += 256) xs4[i] = xg[i];
    float av = asrc[r * DOUT + lane];
    float dv = adst[r * DOUT + lane];
    __syncthreads();

    float acc[8];
#pragma unroll
    for (int i = 0; i < 8; ++i) acc[i] = 0.f;
    const int rbase = warp * 8;
#pragma unroll 2
    for (int k4 = 0; k4 < INP / 4; ++k4) {
        float4 wv = *(const float4*)(&Wt[lane * WS + k4 * 4]);
#pragma unroll
        for (int rr = 0; rr < 8; ++rr) {
            float4 xv = *(const float4*)(&xs[(rbase + rr) * INP + k4 * 4]);  // wave-uniform broadcast
            acc[rr] = fmaf(xv.x, wv.x, acc[rr]);
            acc[rr] = fmaf(xv.y, wv.y, acc[rr]);
            acc[rr] = fmaf(xv.z, wv.z, acc[rr]);
            acc[rr] = fmaf(xv.w, wv.w, acc[rr]);
        }
    }
#pragma unroll
    for (int rr = 0; rr < 8; ++rr) {
        int node = row0 + rbase + rr;
        h[((size_t)r * NN + node) * DOUT + lane] = acc[rr];
        float s1 = acc[rr] * av, s2 = acc[rr] * dv;
#pragma unroll
        for (int off = 32; off; off >>= 1) {
            s1 += __shfl_xor(s1, off);
            s2 += __shfl_xor(s2, off);
        }
        if (lane == 0) { als[r * NN + node] = s1; ald[r * NN + node] = s2; }
    }
}

// ---------------- bucketed CSR build (once per call, shared by both layers) ----------------

// per-bucket edge histogram
__global__ __launch_bounds__(256) void bucket_hist(
    const int* __restrict__ ei0, const int* __restrict__ ei1, const int* __restrict__ ei2,
    unsigned* __restrict__ bcnt)
{
    int e = blockIdx.x * 256 + threadIdx.x;
    if (e >= EE) return;
    int r = blockIdx.y;
    const int* ei = (r == 0) ? ei0 : ((r == 1) ? ei1 : ei2);
    int idx = r * NN + ei[EE + e];
    atomicAdd(&bcnt[idx >> 8], 1u);
}

// exclusive scan of 1172 bucket counts (single block); bbase[NBUCK] = total; bcur = bbase copy
__global__ __launch_bounds__(256) void bucket_scan(
    const unsigned* __restrict__ bcnt, unsigned* __restrict__ bbase, unsigned* __restrict__ bcur)
{
    __shared__ unsigned s[NBUCK];
    int t = threadIdx.x;
    for (int i = t; i < NBUCK; i += 256) s[i] = bcnt[i];
    __syncthreads();
    if (t == 0) {
        unsigned run = 0;
        for (int i = 0; i < NBUCK; ++i) { unsigned x = s[i]; s[i] = run; run += x; }
        bbase[NBUCK] = run;   // = 3M
    }
    __syncthreads();
    for (int i = t; i < NBUCK; i += 256) { bbase[i] = s[i]; bcur[i] = s[i]; }
}

// scatter packed (loc<<24 | src) into contiguous bucket regions (sequential within bucket -> coalescing in L2)
__global__ __launch_bounds__(256) void pair_scatter(
    const int* __restrict__ ei0, const int* __restrict__ ei1, const int* __restrict__ ei2,
    unsigned* __restrict__ bcur, unsigned* __restrict__ packed)
{
    int e = blockIdx.x * 256 + threadIdx.x;
    if (e >= EE) return;
    int r = blockIdx.y;
    const int* ei = (r == 0) ? ei0 : ((r == 1) ? ei1 : ei2);
    int src = ei[e];
    int idx = r * NN + ei[EE + e];
    unsigned pos = atomicAdd(&bcur[idx >> 8], 1u);
    packed[pos] = (unsigned)src | ((unsigned)(idx & 255) << 24);
}

// one block per bucket: LDS sort-by-local-segment; write off[] and csr_src (IN PLACE over packed)
__global__ __launch_bounds__(256) void bucket_build(
    unsigned* __restrict__ packed,        // in: pairs; out: csr_src (same buffer)
    const unsigned* __restrict__ bbase,   // [NBUCK+1]
    unsigned* __restrict__ off)           // [NR]
{
    __shared__ unsigned sp[BCAP];         // 16 KB pairs
    __shared__ unsigned ssrc[BCAP];       // 16 KB ordered srcs
    __shared__ unsigned scnt[BSEG];       // local counts
    __shared__ unsigned scur[BSEG];       // local cursors
    __shared__ unsigned tsum[BSEG];       // scan temp
    const int b = blockIdx.x;
    const int t = threadIdx.x;
    const unsigned base = bbase[b];
    int cnt = (int)(bbase[b + 1] - base);
    if (cnt > BCAP) cnt = BCAP;           // statistically impossible; guards LDS
    for (int i = t; i < cnt; i += 256) sp[i] = packed[base + i];
    scnt[t] = 0;
    __syncthreads();
    for (int i = t; i < cnt; i += 256) atomicAdd(&scnt[sp[i] >> 24], 1u);
    __syncthreads();
    // exclusive scan of 256 counts (Hillis-Steele in LDS)
    unsigned v = scnt[t];
    tsum[t] = v;
    __syncthreads();
    unsigned val = v;
    for (int d = 1; d < 256; d <<= 1) {
        unsigned add = (t >= d) ? tsum[t - d] : 0u;
        __syncthreads();
        val += add;
        tsum[t] = val;
        __syncthreads();
    }
    unsigned excl = val - v;
    scur[t] = excl;
    const int segs = (NR - b * BSEG < BSEG) ? (NR - b * BSEG) : BSEG;
    if (t < segs) off[b * BSEG + t] = base + excl;
    __syncthreads();
    for (int i = t; i < cnt; i += 256) {
        unsigned p = sp[i];
        unsigned pos = atomicAdd(&scur[p >> 24], 1u);
        ssrc[pos] = p & 0x00FFFFFFu;
    }
    __syncthreads();
    for (int i = t; i < cnt; i += 256) packed[base + i] = ssrc[i];  // streaming write
}

// ---------------- fused per-layer aggregation: online segment-softmax + weighted gather ----------------
template<bool L1>
__global__ __launch_bounds__(256) void aggregate(
    const int* __restrict__ csr_src, const unsigned* __restrict__ off,
    const float* __restrict__ h,     // [R, NN, 64]
    const float* __restrict__ als, const float* __restrict__ ald,  // [R, NN]
    const float* __restrict__ bias,  // [R, 64]
    float* __restrict__ outp)        // [NN, 64]
{
    int node = blockIdx.x * 4 + (threadIdx.x >> 6);
    if (node >= NN) return;
    int lane = threadIdx.x & 63;
    float total = 0.f;
#pragma unroll
    for (int r = 0; r < RRR; ++r) {
        int idx = r * NN + node;
        unsigned start = off[idx];
        unsigned end = (idx == NR - 1) ? (unsigned)((size_t)RRR * EE) : off[idx + 1];
        int cnt = (int)(end - start);
        if (cnt <= 0) continue;
        float aldv = ald[idx];
        const float* hr = h + (size_t)r * NN * DOUT;
        const float* alsr = als + (size_t)r * NN;
        float m = -3.4e38f, den = 0.f, acc = 0.f;
        int src_nxt = csr_src[start];
        for (int j = 0; j < cnt; ++j) {
            int src = src_nxt;
            if (j + 1 < cnt) src_nxt = csr_src[start + j + 1];   // prefetch next index
            float hv = hr[(size_t)src * DOUT + lane];            // coalesced 256B, LLC-resident
            float sv = alsr[src] + aldv;                          // wave-uniform
            float lr = (sv > 0.f) ? sv : SLOPE * sv;
            if (lr > m) {                                         // wave-uniform branch
                float sc = __expf(m - lr);                        // 0 on first edge
                den *= sc; acc *= sc; m = lr;
            }
            float p = __expf(lr - m);
            den += p;
            acc = fmaf(p, hv, acc);
        }
        total += acc / den;
    }
    float bsum = bias[lane] + bias[64 + lane] + bias[128 + lane];
    float v = (total + bsum) * (1.0f / 3.0f);
    if (L1) {
        float ss = v * v;
#pragma unroll
        for (int o = 32; o; o >>= 1) ss += __shfl_xor(ss, o);
        float d = fmaxf(sqrtf(ss), 1e-12f);
        v = fmaxf(v / d, 0.f);
    }
    outp[(size_t)node * DOUT + lane] = v;
}

// ---------------- launch ----------------
extern "C" void kernel_launch(void* const* d_in, const int* in_sizes, int n_in,
                              void* d_out, int out_size, void* d_ws, size_t ws_size,
                              hipStream_t stream) {
    const float* x   = (const float*)d_in[0];
    const int* ei0   = (const int*)d_in[1];
    const int* ei1   = (const int*)d_in[2];
    const int* ei2   = (const int*)d_in[3];
    const float* W1  = (const float*)d_in[4];
    const float* as1 = (const float*)d_in[5];
    const float* ad1 = (const float*)d_in[6];
    const float* b1  = (const float*)d_in[7];
    const float* W2  = (const float*)d_in[8];
    const float* as2 = (const float*)d_in[9];
    const float* ad2 = (const float*)d_in[10];
    const float* b2  = (const float*)d_in[11];
    float* out = (float*)d_out;

    // workspace carve-up (4B units): ~118 MB
    float* ws = (float*)d_ws;
    size_t off_u = 0;
    float* h        = ws + off_u; off_u += (size_t)RRR * NN * DOUT;  // 19.2M
    float* als      = ws + off_u; off_u += (size_t)RRR * NN;
    float* ald      = ws + off_u; off_u += (size_t)RRR * NN;
    unsigned* packed= (unsigned*)(ws + off_u); off_u += (size_t)RRR * EE;  // 3M; becomes csr_src
    unsigned* off   = (unsigned*)(ws + off_u); off_u += NR;
    unsigned* bcnt  = (unsigned*)(ws + off_u); off_u += NBUCK;
    unsigned* bbase = (unsigned*)(ws + off_u); off_u += NBUCK + 1;
    unsigned* bcur  = (unsigned*)(ws + off_u); off_u += NBUCK;
    float* hmid     = ws + off_u; off_u += (size_t)NN * DOUT;        // 6.4M

    dim3 blk(256);
    dim3 gG(NN / 32, RRR);            // 3125 x 3
    dim3 gE((EE + 255) / 256, RRR);   // 3907 x 3
    int gA = NN / 4;                  // 25000

    // ---- CSR build (shared by both layers) ----
    hipMemsetAsync(bcnt, 0, (size_t)NBUCK * sizeof(unsigned), stream);
    bucket_hist<<<gE, blk, 0, stream>>>(ei0, ei1, ei2, bcnt);
    bucket_scan<<<1, blk, 0, stream>>>(bcnt, bbase, bcur);
    pair_scatter<<<gE, blk, 0, stream>>>(ei0, ei1, ei2, bcur, packed);
    bucket_build<<<NBUCK, blk, 0, stream>>>(packed, bbase, off);
    const int* csr_src = (const int*)packed;

    // ---- layer 1 ----
    gemm_att<DIN><<<gG, blk, 0, stream>>>(x, W1, as1, ad1, h, als, ald);
    aggregate<true><<<gA, blk, 0, stream>>>(csr_src, off, h, als, ald, b1, hmid);

    // ---- layer 2 ----
    gemm_att<DOUT><<<gG, blk, 0, stream>>>(hmid, W2, as2, ad2, h, als, ald);
    aggregate<false><<<gA, blk, 0, stream>>>(csr_src, off, h, als, ald, b2, out);
}

// Round 4
// 736.457 us; speedup vs baseline: 2.9408x; 2.9408x over previous
//
#include <hip/hip_runtime.h>
#include <hip/hip_bf16.h>
#include <math.h>

constexpr int NN = 100000;
constexpr int EE = 1000000;
constexpr int RRR = 3;
constexpr int DIN = 128;
constexpr int DOUT = 64;
constexpr float SLOPE = 0.2f;
constexpr int NR = RRR * NN;                    // 300000 segments (relation-major)
constexpr int BSEG = 256;                       // segments per bucket
constexpr int NBUCK = (NR + BSEG - 1) / BSEG;   // 1172
constexpr int BCAP = 4096;                      // max edges/bucket (mean 2560, sigma ~51)
constexpr int CHUNK_E = 8192;                   // edges per chunk-block
constexpr int NCH_PER_R = (EE + CHUNK_E - 1) / CHUNK_E;   // 123
constexpr int NCH = RRR * NCH_PER_R;            // 369
constexpr int MT = NBUCK * NCH;                 // 432468 matrix entries
constexpr int SCAN_CHUNK = 1024;
constexpr int NSCB = (MT + SCAN_CHUNK - 1) / SCAN_CHUNK;  // 423

// ---------------- GEMM + attention logits ----------------
// h[r] = x @ W[r]; als[r][n] = h[r][n]·a_src[r]; ald[r][n] = h[r][n]·a_dst[r]
template<int INP>
__global__ __launch_bounds__(256) void gemm_att(
    const float* __restrict__ x,     // [NN, INP]
    const float* __restrict__ W,     // [R, INP, 64]
    const float* __restrict__ asrc,  // [R, 64]
    const float* __restrict__ adst,  // [R, 64]
    float* __restrict__ h,           // [R, NN, 64]
    float* __restrict__ als,         // [R, NN]
    float* __restrict__ ald)         // [R, NN]
{
    constexpr int WS = INP + 4;           // stride 132/68 floats: conflict-free b128
    __shared__ float Wt[64 * WS];         // W transposed: Wt[col][k]
    __shared__ float xs[32 * INP];        // 32 x-rows
    const int r = blockIdx.y;
    const int row0 = blockIdx.x * 32;     // NN/32 = 3125 exact
    const int t = threadIdx.x;
    const int lane = t & 63;
    const int warp = t >> 6;

    const float* Wr = W + r * (INP * DOUT);
    for (int idx = t; idx < INP * DOUT; idx += 256) {
        int k = idx >> 6, c = idx & 63;
        Wt[c * WS + k] = Wr[idx];
    }
    const float4* xg = (const float4*)(x + (size_t)row0 * INP);
    float4* xs4 = (float4*)xs;
    for (int i = t; i < 32 * INP / 4; i += 256) xs4[i] = xg[i];
    float av = asrc[r * DOUT + lane];
    float dv = adst[r * DOUT + lane];
    __syncthreads();

    float acc[8];
#pragma unroll
    for (int i = 0; i < 8; ++i) acc[i] = 0.f;
    const int rbase = warp * 8;
#pragma unroll 2
    for (int k4 = 0; k4 < INP / 4; ++k4) {
        float4 wv = *(const float4*)(&Wt[lane * WS + k4 * 4]);
#pragma unroll
        for (int rr = 0; rr < 8; ++rr) {
            float4 xv = *(const float4*)(&xs[(rbase + rr) * INP + k4 * 4]);  // wave-uniform broadcast
            acc[rr] = fmaf(xv.x, wv.x, acc[rr]);
            acc[rr] = fmaf(xv.y, wv.y, acc[rr]);
            acc[rr] = fmaf(xv.z, wv.z, acc[rr]);
            acc[rr] = fmaf(xv.w, wv.w, acc[rr]);
        }
    }
#pragma unroll
    for (int rr = 0; rr < 8; ++rr) {
        int node = row0 + rbase + rr;
        h[((size_t)r * NN + node) * DOUT + lane] = acc[rr];
        float s1 = acc[rr] * av, s2 = acc[rr] * dv;
#pragma unroll
        for (int off = 32; off; off >>= 1) {
            s1 += __shfl_xor(s1, off);
            s2 += __shfl_xor(s2, off);
        }
        if (lane == 0) { als[r * NN + node] = s1; ald[r * NN + node] = s2; }
    }
}

// ---------------- CSR build: deterministic counting-sort, NO global atomics ----------------

// pass A: per-chunk LDS histogram of buckets -> M[bucket][chunk]
__global__ __launch_bounds__(256) void chunk_hist(
    const int* __restrict__ ei0, const int* __restrict__ ei1, const int* __restrict__ ei2,
    unsigned* __restrict__ M)
{
    __shared__ unsigned hist[NBUCK];
    const int r = blockIdx.y, bx = blockIdx.x;
    const int* ei = (r == 0) ? ei0 : ((r == 1) ? ei1 : ei2);
    const int t = threadIdx.x;
    for (int i = t; i < NBUCK; i += 256) hist[i] = 0;
    __syncthreads();
    const int e0 = bx * CHUNK_E;
    const int e1 = (e0 + CHUNK_E < EE) ? e0 + CHUNK_E : EE;
    for (int e = e0 + t; e < e1; e += 256) {
        int idx = r * NN + ei[EE + e];
        atomicAdd(&hist[idx >> 8], 1u);      // LDS atomic: fast, uncontended
    }
    __syncthreads();
    const int c = r * NCH_PER_R + bx;
    for (int i = t; i < NBUCK; i += 256) M[(size_t)i * NCH + c] = hist[i];
}

// hierarchical exclusive scan of M (in place), bucket-major order
__global__ __launch_bounds__(256) void scan_block(unsigned* __restrict__ data, unsigned* __restrict__ bsum)
{
    __shared__ unsigned tsum[256];
    const int base = blockIdx.x * SCAN_CHUNK;
    const int t = threadIdx.x;
    const int i0 = base + t * 4;
    unsigned v[4];
#pragma unroll
    for (int k = 0; k < 4; ++k) v[k] = (i0 + k < MT) ? data[i0 + k] : 0u;
    unsigned run = 0;
#pragma unroll
    for (int k = 0; k < 4; ++k) { unsigned x = v[k]; v[k] = run; run += x; }
    tsum[t] = run;
    __syncthreads();
    unsigned val = run;
    for (int d = 1; d < 256; d <<= 1) {
        unsigned add = (t >= d) ? tsum[t - d] : 0u;
        __syncthreads();
        val += add;
        tsum[t] = val;
        __syncthreads();
    }
    unsigned texcl = val - run;
    if (t == 255) bsum[blockIdx.x] = val;
#pragma unroll
    for (int k = 0; k < 4; ++k)
        if (i0 + k < MT) data[i0 + k] = texcl + v[k];
}

__global__ __launch_bounds__(256) void scan_bsums(unsigned* __restrict__ bsum)
{
    __shared__ unsigned s[NSCB];
    int t = threadIdx.x;
    for (int i = t; i < NSCB; i += 256) s[i] = bsum[i];
    __syncthreads();
    if (t == 0) {
        unsigned run = 0;
        for (int i = 0; i < NSCB; ++i) { unsigned x = s[i]; s[i] = run; run += x; }
    }
    __syncthreads();
    for (int i = t; i < NSCB; i += 256) bsum[i] = s[i];
}

__global__ __launch_bounds__(256) void add_off(unsigned* __restrict__ data, const unsigned* __restrict__ bsum)
{
    int i = blockIdx.x * 256 + threadIdx.x;
    if (i >= MT) return;
    data[i] += bsum[i / SCAN_CHUNK];
}

// pass B: scatter packed (loc<<24 | src) to exact positions (LDS cursors from scanned M)
__global__ __launch_bounds__(256) void chunk_scatter(
    const int* __restrict__ ei0, const int* __restrict__ ei1, const int* __restrict__ ei2,
    const unsigned* __restrict__ Ms, unsigned* __restrict__ packed)
{
    __shared__ unsigned cur[NBUCK];
    const int r = blockIdx.y, bx = blockIdx.x;
    const int* ei = (r == 0) ? ei0 : ((r == 1) ? ei1 : ei2);
    const int t = threadIdx.x;
    const int c = r * NCH_PER_R + bx;
    for (int i = t; i < NBUCK; i += 256) cur[i] = Ms[(size_t)i * NCH + c];
    __syncthreads();
    const int e0 = bx * CHUNK_E;
    const int e1 = (e0 + CHUNK_E < EE) ? e0 + CHUNK_E : EE;
    for (int e = e0 + t; e < e1; e += 256) {
        int src = ei[e];
        int idx = r * NN + ei[EE + e];
        unsigned pos = atomicAdd(&cur[idx >> 8], 1u);   // LDS atomic only
        packed[pos] = (unsigned)src | ((unsigned)(idx & 255) << 24);
    }
}

// one block per bucket: LDS sort-by-local-segment; write off[] and csr_src (IN PLACE over packed)
__global__ __launch_bounds__(256) void bucket_build(
    unsigned* __restrict__ packed,        // in: pairs; out: csr_src (same buffer)
    const unsigned* __restrict__ Ms,      // scanned matrix: Ms[b*NCH] = bucket base
    unsigned* __restrict__ off)           // [NR]
{
    __shared__ unsigned sp[BCAP];         // 16 KB pairs
    __shared__ unsigned ssrc[BCAP];       // 16 KB ordered srcs
    __shared__ unsigned scnt[BSEG];
    __shared__ unsigned scur[BSEG];
    __shared__ unsigned tsum[BSEG];
    const int b = blockIdx.x;
    const int t = threadIdx.x;
    const unsigned base = Ms[(size_t)b * NCH];
    const unsigned next = (b + 1 < NBUCK) ? Ms[(size_t)(b + 1) * NCH] : (unsigned)((size_t)RRR * EE);
    int cnt = (int)(next - base);
    if (cnt > BCAP) cnt = BCAP;           // statistically impossible; guards LDS
    for (int i = t; i < cnt; i += 256) sp[i] = packed[base + i];
    scnt[t] = 0;
    __syncthreads();
    for (int i = t; i < cnt; i += 256) atomicAdd(&scnt[sp[i] >> 24], 1u);
    __syncthreads();
    unsigned v = scnt[t];
    tsum[t] = v;
    __syncthreads();
    unsigned val = v;
    for (int d = 1; d < 256; d <<= 1) {
        unsigned add = (t >= d) ? tsum[t - d] : 0u;
        __syncthreads();
        val += add;
        tsum[t] = val;
        __syncthreads();
    }
    unsigned excl = val - v;
    scur[t] = excl;
    const int segs = (NR - b * BSEG < BSEG) ? (NR - b * BSEG) : BSEG;
    if (t < segs) off[b * BSEG + t] = base + excl;
    __syncthreads();
    for (int i = t; i < cnt; i += 256) {
        unsigned p = sp[i];
        unsigned pos = atomicAdd(&scur[p >> 24], 1u);
        ssrc[pos] = p & 0x00FFFFFFu;
    }
    __syncthreads();
    for (int i = t; i < cnt; i += 256) packed[base + i] = ssrc[i];  // streaming write
}

// ---------------- fused per-layer aggregation: online segment-softmax + weighted gather ----------------
template<bool L1>
__global__ __launch_bounds__(256) void aggregate(
    const int* __restrict__ csr_src, const unsigned* __restrict__ off,
    const float* __restrict__ h,     // [R, NN, 64]
    const float* __restrict__ als, const float* __restrict__ ald,  // [R, NN]
    const float* __restrict__ bias,  // [R, 64]
    float* __restrict__ outp)        // [NN, 64]
{
    int node = blockIdx.x * 4 + (threadIdx.x >> 6);
    if (node >= NN) return;
    int lane = threadIdx.x & 63;
    float total = 0.f;
#pragma unroll
    for (int r = 0; r < RRR; ++r) {
        int idx = r * NN + node;
        unsigned start = off[idx];
        unsigned end = (idx == NR - 1) ? (unsigned)((size_t)RRR * EE) : off[idx + 1];
        int cnt = (int)(end - start);
        if (cnt <= 0) continue;
        float aldv = ald[idx];
        const float* hr = h + (size_t)r * NN * DOUT;
        const float* alsr = als + (size_t)r * NN;
        float m = -3.4e38f, den = 0.f, acc = 0.f;
        int src_nxt = csr_src[start];
        for (int j = 0; j < cnt; ++j) {
            int src = src_nxt;
            if (j + 1 < cnt) src_nxt = csr_src[start + j + 1];   // prefetch next index
            float hv = hr[(size_t)src * DOUT + lane];            // coalesced 256B, LLC-resident
            float sv = alsr[src] + aldv;                          // wave-uniform
            float lr = (sv > 0.f) ? sv : SLOPE * sv;
            if (lr > m) {                                         // wave-uniform branch
                float sc = __expf(m - lr);                        // 0 on first edge
                den *= sc; acc *= sc; m = lr;
            }
            float p = __expf(lr - m);
            den += p;
            acc = fmaf(p, hv, acc);
        }
        total += acc / den;
    }
    float bsum = bias[lane] + bias[64 + lane] + bias[128 + lane];
    float v = (total + bsum) * (1.0f / 3.0f);
    if (L1) {
        float ss = v * v;
#pragma unroll
        for (int o = 32; o; o >>= 1) ss += __shfl_xor(ss, o);
        float d = fmaxf(sqrtf(ss), 1e-12f);
        v = fmaxf(v / d, 0.f);
    }
    outp[(size_t)node * DOUT + lane] = v;
}

// ---------------- launch ----------------
extern "C" void kernel_launch(void* const* d_in, const int* in_sizes, int n_in,
                              void* d_out, int out_size, void* d_ws, size_t ws_size,
                              hipStream_t stream) {
    const float* x   = (const float*)d_in[0];
    const int* ei0   = (const int*)d_in[1];
    const int* ei1   = (const int*)d_in[2];
    const int* ei2   = (const int*)d_in[3];
    const float* W1  = (const float*)d_in[4];
    const float* as1 = (const float*)d_in[5];
    const float* ad1 = (const float*)d_in[6];
    const float* b1  = (const float*)d_in[7];
    const float* W2  = (const float*)d_in[8];
    const float* as2 = (const float*)d_in[9];
    const float* ad2 = (const float*)d_in[10];
    const float* b2  = (const float*)d_in[11];
    float* out = (float*)d_out;

    // workspace carve-up (4B units): ~118 MB (M/bsum overlap hmid — M dead before aggregate runs)
    float* ws = (float*)d_ws;
    size_t off_u = 0;
    float* h        = ws + off_u; off_u += (size_t)RRR * NN * DOUT;       // 19.2M
    float* als      = ws + off_u; off_u += (size_t)RRR * NN;
    float* ald      = ws + off_u; off_u += (size_t)RRR * NN;
    unsigned* packed= (unsigned*)(ws + off_u); off_u += (size_t)RRR * EE; // 3M; becomes csr_src
    unsigned* off   = (unsigned*)(ws + off_u); off_u += NR;
    float* hmid     = ws + off_u;                                          // 6.4M floats
    unsigned* M     = (unsigned*)hmid;          // overlaps hmid: MT=432k < 6.4M; dead before layer 1
    unsigned* bsum  = M + MT;                   // +423, still < 6.4M

    dim3 blk(256);
    dim3 gG(NN / 32, RRR);            // 3125 x 3
    dim3 gC(NCH_PER_R, RRR);          // 123 x 3
    int gA = NN / 4;                  // 25000

    // ---- CSR build (deterministic, no global atomics; shared by both layers) ----
    chunk_hist<<<gC, blk, 0, stream>>>(ei0, ei1, ei2, M);
    scan_block<<<NSCB, blk, 0, stream>>>(M, bsum);
    scan_bsums<<<1, blk, 0, stream>>>(bsum);
    add_off<<<(MT + 255) / 256, blk, 0, stream>>>(M, bsum);
    chunk_scatter<<<gC, blk, 0, stream>>>(ei0, ei1, ei2, M, packed);
    bucket_build<<<NBUCK, blk, 0, stream>>>(packed, M, off);
    const int* csr_src = (const int*)packed;

    // ---- layer 1 ----
    gemm_att<DIN><<<gG, blk, 0, stream>>>(x, W1, as1, ad1, h, als, ald);
    aggregate<true><<<gA, blk, 0, stream>>>(csr_src, off, h, als, ald, b1, hmid);

    // ---- layer 2 ----
    gemm_att<DOUT><<<gG, blk, 0, stream>>>(hmid, W2, as2, ad2, h, als, ald);
    aggregate<false><<<gA, blk, 0, stream>>>(csr_src, off, h, als, ald, b2, out);
}

// Round 5
// 667.650 us; speedup vs baseline: 3.2439x; 1.1031x over previous
//
#include <hip/hip_runtime.h>
#include <hip/hip_bf16.h>
#include <math.h>

constexpr int NN = 100000;
constexpr int EE = 1000000;
constexpr int RRR = 3;
constexpr int DIN = 128;
constexpr int DOUT = 64;
constexpr float SLOPE = 0.2f;
constexpr int NR = RRR * NN;                    // 300000 segments (relation-major)
constexpr int BSEG = 256;                       // segments per bucket
constexpr int NBUCK = (NR + BSEG - 1) / BSEG;   // 1172
constexpr int BCAP = 4096;                      // max edges/bucket (mean 2560, sigma ~51)
constexpr int CHUNK_E = 8192;                   // edges per chunk-block
constexpr int NCH_PER_R = (EE + CHUNK_E - 1) / CHUNK_E;   // 123
constexpr int NCH = RRR * NCH_PER_R;            // 369
constexpr int MT = NBUCK * NCH;                 // 432468 matrix entries
constexpr int SCAN_CHUNK = 1024;
constexpr int NSCB = (MT + SCAN_CHUNK - 1) / SCAN_CHUNK;  // 423

// ---------------- W pre-transpose: Wt[r][c][k] = W[r][k][c] ----------------
__global__ __launch_bounds__(256) void transpose_W(
    const float* __restrict__ W1, const float* __restrict__ W2,
    float* __restrict__ Wt1, float* __restrict__ Wt2)
{
    int m = blockIdx.x;     // 0..2: W1 (K=128), 3..5: W2 (K=64)
    int t = threadIdx.x;
    if (m < 3) {
        const float* src = W1 + (size_t)m * DIN * DOUT;
        float* dst = Wt1 + (size_t)m * DIN * DOUT;
        for (int i = t; i < DIN * DOUT; i += 256) {
            int k = i >> 6, c = i & 63;
            dst[c * DIN + k] = src[i];
        }
    } else {
        const float* src = W2 + (size_t)(m - 3) * DOUT * DOUT;
        float* dst = Wt2 + (size_t)(m - 3) * DOUT * DOUT;
        for (int i = t; i < DOUT * DOUT; i += 256) {
            int k = i >> 6, c = i & 63;
            dst[c * DOUT + k] = src[i];
        }
    }
}

// ---------------- GEMM + attention logits, v2: lane=row, scalar W loads ----------------
// block: 256 thr = 4 waves; computes 64 rows (lane=row) x 64 cols (wave owns 16 cols).
template<int INP>
__global__ __launch_bounds__(256) void gemm_att2(
    const float* __restrict__ x,     // [NN, INP]
    const float* __restrict__ Wt,    // [R, 64, INP] (k-contiguous per col)
    const float* __restrict__ asrc,  // [R, 64]
    const float* __restrict__ adst,  // [R, 64]
    float* __restrict__ h,           // [R, NN, 64]
    float* __restrict__ als,         // [R, NN]
    float* __restrict__ ald)         // [R, NN]
{
    constexpr int XS = INP + 1;                 // odd word stride -> conflict-free b128
    constexpr int KLOG = (INP == 128) ? 5 : 4;  // log2(INP/4)
    __shared__ float smem[64 * XS];             // xs during k-loop; out[64][65] after
    __shared__ float parts[512];                // als/ald partials: [2][4][64]
    const int t = threadIdx.x;
    const int lane = t & 63;
    const int warp_s = __builtin_amdgcn_readfirstlane(t >> 6);
    const int r = blockIdx.y;
    const int row0 = blockIdx.x * 64;

    // stage x rows (clamped for tail block), coalesced float4
    for (int idx = t; idx < 64 * (INP / 4); idx += 256) {
        int row = idx >> KLOG, kk = idx & ((INP / 4) - 1);
        int grow = row0 + row; if (grow >= NN) grow = NN - 1;
        *(float4*)&smem[row * XS + kk * 4] = *(const float4*)(x + (size_t)grow * INP + kk * 4);
    }
    __syncthreads();

    float acc[16];
#pragma unroll
    for (int i = 0; i < 16; ++i) acc[i] = 0.f;
    const float* wbase = Wt + ((size_t)r * 64 + warp_s * 16) * INP;

#pragma unroll 1
    for (int k4 = 0; k4 < INP / 4; ++k4) {
        float4 xv = *(const float4*)&smem[lane * XS + k4 * 4];   // per-lane, conflict-free
#pragma unroll
        for (int i = 0; i < 16; ++i) {
            float4 wv = *(const float4*)(wbase + i * INP + k4 * 4);  // wave-uniform -> s_load
            acc[i] = fmaf(xv.x, wv.x, acc[i]);
            acc[i] = fmaf(xv.y, wv.y, acc[i]);
            acc[i] = fmaf(xv.z, wv.z, acc[i]);
            acc[i] = fmaf(xv.w, wv.w, acc[i]);
        }
    }

    // als/ald partials from registers (cols warp_s*16..+15)
    {
        const float* av = asrc + r * 64 + warp_s * 16;
        const float* dv = adst + r * 64 + warp_s * 16;
        float ps = 0.f, pd = 0.f;
#pragma unroll
        for (int i = 0; i < 16; ++i) { ps = fmaf(acc[i], av[i], ps); pd = fmaf(acc[i], dv[i], pd); }
        parts[warp_s * 64 + lane] = ps;
        parts[256 + warp_s * 64 + lane] = pd;
    }

    __syncthreads();                 // xs fully consumed; reuse smem as out[64][65]
    float* outb = smem;
#pragma unroll
    for (int i = 0; i < 16; ++i) outb[lane * 65 + warp_s * 16 + i] = acc[i];
    __syncthreads();

    const int nrows = (NN - row0 < 64) ? (NN - row0) : 64;
    for (int idx = t; idx < nrows * 64; idx += 256) {
        int row = idx >> 6, c = idx & 63;
        h[((size_t)r * NN + row0 + row) * 64 + c] = outb[row * 65 + c];   // coalesced
    }
    if (t < nrows) {
        float s = parts[t] + parts[64 + t] + parts[128 + t] + parts[192 + t];
        float d = parts[256 + t] + parts[320 + t] + parts[384 + t] + parts[448 + t];
        als[r * NN + row0 + t] = s;
        ald[r * NN + row0 + t] = d;
    }
}

// ---------------- CSR build: deterministic counting-sort, NO global atomics ----------------

__global__ __launch_bounds__(256) void chunk_hist(
    const int* __restrict__ ei0, const int* __restrict__ ei1, const int* __restrict__ ei2,
    unsigned* __restrict__ M)
{
    __shared__ unsigned hist[NBUCK];
    const int r = blockIdx.y, bx = blockIdx.x;
    const int* ei = (r == 0) ? ei0 : ((r == 1) ? ei1 : ei2);
    const int t = threadIdx.x;
    for (int i = t; i < NBUCK; i += 256) hist[i] = 0;
    __syncthreads();
    const int e0 = bx * CHUNK_E;
    const int e1 = (e0 + CHUNK_E < EE) ? e0 + CHUNK_E : EE;
    for (int e = e0 + t; e < e1; e += 256) {
        int idx = r * NN + ei[EE + e];
        atomicAdd(&hist[idx >> 8], 1u);      // LDS atomic
    }
    __syncthreads();
    const int c = r * NCH_PER_R + bx;
    for (int i = t; i < NBUCK; i += 256) M[(size_t)i * NCH + c] = hist[i];
}

__global__ __launch_bounds__(256) void scan_block(unsigned* __restrict__ data, unsigned* __restrict__ bsum)
{
    __shared__ unsigned tsum[256];
    const int base = blockIdx.x * SCAN_CHUNK;
    const int t = threadIdx.x;
    const int i0 = base + t * 4;
    unsigned v[4];
#pragma unroll
    for (int k = 0; k < 4; ++k) v[k] = (i0 + k < MT) ? data[i0 + k] : 0u;
    unsigned run = 0;
#pragma unroll
    for (int k = 0; k < 4; ++k) { unsigned x = v[k]; v[k] = run; run += x; }
    tsum[t] = run;
    __syncthreads();
    unsigned val = run;
    for (int d = 1; d < 256; d <<= 1) {
        unsigned add = (t >= d) ? tsum[t - d] : 0u;
        __syncthreads();
        val += add;
        tsum[t] = val;
        __syncthreads();
    }
    unsigned texcl = val - run;
    if (t == 255) bsum[blockIdx.x] = val;
#pragma unroll
    for (int k = 0; k < 4; ++k)
        if (i0 + k < MT) data[i0 + k] = texcl + v[k];
}

__global__ __launch_bounds__(256) void scan_bsums(unsigned* __restrict__ bsum)
{
    __shared__ unsigned s[NSCB];
    int t = threadIdx.x;
    for (int i = t; i < NSCB; i += 256) s[i] = bsum[i];
    __syncthreads();
    if (t == 0) {
        unsigned run = 0;
        for (int i = 0; i < NSCB; ++i) { unsigned x = s[i]; s[i] = run; run += x; }
    }
    __syncthreads();
    for (int i = t; i < NSCB; i += 256) bsum[i] = s[i];
}

__global__ __launch_bounds__(256) void add_off(unsigned* __restrict__ data, const unsigned* __restrict__ bsum)
{
    int i = blockIdx.x * 256 + threadIdx.x;
    if (i >= MT) return;
    data[i] += bsum[i / SCAN_CHUNK];
}

__global__ __launch_bounds__(256) void chunk_scatter(
    const int* __restrict__ ei0, const int* __restrict__ ei1, const int* __restrict__ ei2,
    const unsigned* __restrict__ Ms, unsigned* __restrict__ packed)
{
    __shared__ unsigned cur[NBUCK];
    const int r = blockIdx.y, bx = blockIdx.x;
    const int* ei = (r == 0) ? ei0 : ((r == 1) ? ei1 : ei2);
    const int t = threadIdx.x;
    const int c = r * NCH_PER_R + bx;
    for (int i = t; i < NBUCK; i += 256) cur[i] = Ms[(size_t)i * NCH + c];
    __syncthreads();
    const int e0 = bx * CHUNK_E;
    const int e1 = (e0 + CHUNK_E < EE) ? e0 + CHUNK_E : EE;
    for (int e = e0 + t; e < e1; e += 256) {
        int src = ei[e];
        int idx = r * NN + ei[EE + e];
        unsigned pos = atomicAdd(&cur[idx >> 8], 1u);   // LDS atomic only
        packed[pos] = (unsigned)src | ((unsigned)(idx & 255) << 24);
    }
}

__global__ __launch_bounds__(256) void bucket_build(
    unsigned* __restrict__ packed,        // in: pairs; out: csr_src (same buffer)
    const unsigned* __restrict__ Ms,      // scanned matrix: Ms[b*NCH] = bucket base
    unsigned* __restrict__ off)           // [NR]
{
    __shared__ unsigned sp[BCAP];
    __shared__ unsigned ssrc[BCAP];
    __shared__ unsigned scnt[BSEG];
    __shared__ unsigned scur[BSEG];
    __shared__ unsigned tsum[BSEG];
    const int b = blockIdx.x;
    const int t = threadIdx.x;
    const unsigned base = Ms[(size_t)b * NCH];
    const unsigned next = (b + 1 < NBUCK) ? Ms[(size_t)(b + 1) * NCH] : (unsigned)((size_t)RRR * EE);
    int cnt = (int)(next - base);
    if (cnt > BCAP) cnt = BCAP;
    for (int i = t; i < cnt; i += 256) sp[i] = packed[base + i];
    scnt[t] = 0;
    __syncthreads();
    for (int i = t; i < cnt; i += 256) atomicAdd(&scnt[sp[i] >> 24], 1u);
    __syncthreads();
    unsigned v = scnt[t];
    tsum[t] = v;
    __syncthreads();
    unsigned val = v;
    for (int d = 1; d < 256; d <<= 1) {
        unsigned add = (t >= d) ? tsum[t - d] : 0u;
        __syncthreads();
        val += add;
        tsum[t] = val;
        __syncthreads();
    }
    unsigned excl = val - v;
    scur[t] = excl;
    const int segs = (NR - b * BSEG < BSEG) ? (NR - b * BSEG) : BSEG;
    if (t < segs) off[b * BSEG + t] = base + excl;
    __syncthreads();
    for (int i = t; i < cnt; i += 256) {
        unsigned p = sp[i];
        unsigned pos = atomicAdd(&scur[p >> 24], 1u);
        ssrc[pos] = p & 0x00FFFFFFu;
    }
    __syncthreads();
    for (int i = t; i < cnt; i += 256) packed[base + i] = ssrc[i];
}

// ---------------- aggregation v2: lane-parallel softmax + readlane-broadcast gather ----------------
// one wave per dst node; per relation: phase 1 = lane-per-edge logits + wave reductions
// (one expf per EDGE, not per edge*lane); phase 2 = per-edge scalar-broadcast fmac.
template<bool L1>
__global__ __launch_bounds__(256) void aggregate2(
    const int* __restrict__ csr_src, const unsigned* __restrict__ off,
    const float* __restrict__ h,     // [R, NN, 64]
    const float* __restrict__ als, const float* __restrict__ ald,  // [R, NN]
    const float* __restrict__ bias,  // [R, 64]
    float* __restrict__ outp)        // [NN, 64]
{
    int node = blockIdx.x * 4 + (threadIdx.x >> 6);
    if (node >= NN) return;
    int lane = threadIdx.x & 63;
    float total = 0.f;
#pragma unroll
    for (int r = 0; r < RRR; ++r) {
        int idx = r * NN + node;
        unsigned start = off[idx];
        unsigned end = (idx == NR - 1) ? (unsigned)((size_t)RRR * EE) : off[idx + 1];
        int cnt = (int)(end - start);
        if (cnt <= 0) continue;
        float aldv = ald[idx];
        const float* hr = h + (size_t)r * NN * DOUT;
        const float* alsr = als + (size_t)r * NN;
        float m = -3.4e38f, den = 0.f, accv = 0.f;
        for (int t0 = 0; t0 < cnt; t0 += 64) {
            int j = t0 + lane;
            bool act = (j < cnt);
            int src = 0;
            float lr = -3.4e38f;
            if (act) {
                src = csr_src[start + j];                 // coalesced
                float sv = alsr[src] + aldv;              // 4B gather
                lr = (sv > 0.f) ? sv : SLOPE * sv;
            }
            float mt = lr;
#pragma unroll
            for (int o = 32; o; o >>= 1) mt = fmaxf(mt, __shfl_xor(mt, o));
            float mnew = fmaxf(m, mt);
            float scale = __expf(m - mnew);               // 0 on first tile, 1 if no change
            den *= scale; accv *= scale; m = mnew;
            float p = act ? __expf(lr - m) : 0.f;
            float ps = p;
#pragma unroll
            for (int o = 32; o; o >>= 1) ps += __shfl_xor(ps, o);
            den += ps;
            int tcnt = cnt - t0; if (tcnt > 64) tcnt = 64;
            for (int j2 = 0; j2 < tcnt; ++j2) {
                int sj = __builtin_amdgcn_readlane(src, j2);                              // SGPR
                float pj = __int_as_float(__builtin_amdgcn_readlane(__float_as_int(p), j2)); // SGPR
                accv = fmaf(pj, hr[(size_t)sj * DOUT + lane], accv);  // scalar base + lane*4
            }
        }
        total += accv / den;
    }
    float bsum = bias[lane] + bias[64 + lane] + bias[128 + lane];
    float v = (total + bsum) * (1.0f / 3.0f);
    if (L1) {
        float ss = v * v;
#pragma unroll
        for (int o = 32; o; o >>= 1) ss += __shfl_xor(ss, o);
        float d = fmaxf(sqrtf(ss), 1e-12f);
        v = fmaxf(v / d, 0.f);
    }
    outp[(size_t)node * DOUT + lane] = v;
}

// ---------------- launch ----------------
extern "C" void kernel_launch(void* const* d_in, const int* in_sizes, int n_in,
                              void* d_out, int out_size, void* d_ws, size_t ws_size,
                              hipStream_t stream) {
    const float* x   = (const float*)d_in[0];
    const int* ei0   = (const int*)d_in[1];
    const int* ei1   = (const int*)d_in[2];
    const int* ei2   = (const int*)d_in[3];
    const float* W1  = (const float*)d_in[4];
    const float* as1 = (const float*)d_in[5];
    const float* ad1 = (const float*)d_in[6];
    const float* b1  = (const float*)d_in[7];
    const float* W2  = (const float*)d_in[8];
    const float* as2 = (const float*)d_in[9];
    const float* ad2 = (const float*)d_in[10];
    const float* b2  = (const float*)d_in[11];
    float* out = (float*)d_out;

    // workspace carve-up (4B units)
    float* ws = (float*)d_ws;
    size_t off_u = 0;
    float* h        = ws + off_u; off_u += (size_t)RRR * NN * DOUT;       // 19.2M
    float* als      = ws + off_u; off_u += (size_t)RRR * NN;
    float* ald      = ws + off_u; off_u += (size_t)RRR * NN;
    unsigned* packed= (unsigned*)(ws + off_u); off_u += (size_t)RRR * EE; // 3M; becomes csr_src
    unsigned* off   = (unsigned*)(ws + off_u); off_u += NR;
    float* Wt1      = ws + off_u; off_u += (size_t)RRR * DIN * DOUT;
    float* Wt2      = ws + off_u; off_u += (size_t)RRR * DOUT * DOUT;
    float* hmid     = ws + off_u;                                          // 6.4M floats
    unsigned* M     = (unsigned*)hmid;          // overlaps hmid: MT=432k < 6.4M; dead before layer 1
    unsigned* bsum  = M + MT;

    dim3 blk(256);
    dim3 gG2((NN + 63) / 64, RRR);    // 1563 x 3
    dim3 gC(NCH_PER_R, RRR);          // 123 x 3
    int gA = NN / 4;                  // 25000

    // ---- CSR build (deterministic, no global atomics; shared by both layers) ----
    chunk_hist<<<gC, blk, 0, stream>>>(ei0, ei1, ei2, M);
    scan_block<<<NSCB, blk, 0, stream>>>(M, bsum);
    scan_bsums<<<1, blk, 0, stream>>>(bsum);
    add_off<<<(MT + 255) / 256, blk, 0, stream>>>(M, bsum);
    chunk_scatter<<<gC, blk, 0, stream>>>(ei0, ei1, ei2, M, packed);
    bucket_build<<<NBUCK, blk, 0, stream>>>(packed, M, off);
    const int* csr_src = (const int*)packed;

    transpose_W<<<6, blk, 0, stream>>>(W1, W2, Wt1, Wt2);

    // ---- layer 1 ----
    gemm_att2<DIN><<<gG2, blk, 0, stream>>>(x, Wt1, as1, ad1, h, als, ald);
    aggregate2<true><<<gA, blk, 0, stream>>>(csr_src, off, h, als, ald, b1, hmid);

    // ---- layer 2 ----
    gemm_att2<DOUT><<<gG2, blk, 0, stream>>>(hmid, Wt2, as2, ad2, h, als, ald);
    aggregate2<false><<<gA, blk, 0, stream>>>(csr_src, off, h, als, ald, b2, out);
}

// Round 6
// 505.478 us; speedup vs baseline: 4.2846x; 1.3208x over previous
//
#include <hip/hip_runtime.h>
#include <hip/hip_bf16.h>
#include <math.h>

constexpr int NN = 100000;
constexpr int EE = 1000000;
constexpr int RRR = 3;
constexpr int DIN = 128;
constexpr int DOUT = 64;
constexpr float SLOPE = 0.2f;
constexpr int NR = RRR * NN;                    // 300000 segments (relation-major)
constexpr int BSEG = 256;                       // segments per bucket
constexpr int NBUCK = (NR + BSEG - 1) / BSEG;   // 1172
constexpr int BCAP = 4096;                      // max edges/bucket (mean 2560, sigma ~51)
constexpr int CHUNK_E = 8192;                   // edges per chunk-block
constexpr int NCH_PER_R = (EE + CHUNK_E - 1) / CHUNK_E;   // 123
constexpr int NCH = RRR * NCH_PER_R;            // 369
constexpr int MT = NBUCK * NCH;                 // 432468 matrix entries
constexpr int SCAN_CHUNK = 1024;
constexpr int NSCB = (MT + SCAN_CHUNK - 1) / SCAN_CHUNK;  // 423

// ---------------- W pre-transpose: Wt[r][c][k] = W[r][k][c] ----------------
__global__ __launch_bounds__(256) void transpose_W(
    const float* __restrict__ W1, const float* __restrict__ W2,
    float* __restrict__ Wt1, float* __restrict__ Wt2)
{
    int m = blockIdx.x;     // 0..2: W1 (K=128), 3..5: W2 (K=64)
    int t = threadIdx.x;
    if (m < 3) {
        const float* src = W1 + (size_t)m * DIN * DOUT;
        float* dst = Wt1 + (size_t)m * DIN * DOUT;
        for (int i = t; i < DIN * DOUT; i += 256) {
            int k = i >> 6, c = i & 63;
            dst[c * DIN + k] = src[i];
        }
    } else {
        const float* src = W2 + (size_t)(m - 3) * DOUT * DOUT;
        float* dst = Wt2 + (size_t)(m - 3) * DOUT * DOUT;
        for (int i = t; i < DOUT * DOUT; i += 256) {
            int k = i >> 6, c = i & 63;
            dst[c * DOUT + k] = src[i];
        }
    }
}

// ---------------- GEMM + attention logits, v2: lane=row, scalar W loads ----------------
template<int INP>
__global__ __launch_bounds__(256) void gemm_att2(
    const float* __restrict__ x,     // [NN, INP]
    const float* __restrict__ Wt,    // [R, 64, INP] (k-contiguous per col)
    const float* __restrict__ asrc,  // [R, 64]
    const float* __restrict__ adst,  // [R, 64]
    float* __restrict__ h,           // [R, NN, 64]
    float* __restrict__ als,         // [R, NN]
    float* __restrict__ ald)         // [R, NN]
{
    constexpr int XS = INP + 1;                 // odd word stride -> conflict-free b128
    constexpr int KLOG = (INP == 128) ? 5 : 4;  // log2(INP/4)
    __shared__ float smem[64 * XS];             // xs during k-loop; out[64][65] after
    __shared__ float parts[512];                // als/ald partials: [2][4][64]
    const int t = threadIdx.x;
    const int lane = t & 63;
    const int warp_s = __builtin_amdgcn_readfirstlane(t >> 6);
    const int r = blockIdx.y;
    const int row0 = blockIdx.x * 64;

    for (int idx = t; idx < 64 * (INP / 4); idx += 256) {
        int row = idx >> KLOG, kk = idx & ((INP / 4) - 1);
        int grow = row0 + row; if (grow >= NN) grow = NN - 1;
        *(float4*)&smem[row * XS + kk * 4] = *(const float4*)(x + (size_t)grow * INP + kk * 4);
    }
    __syncthreads();

    float acc[16];
#pragma unroll
    for (int i = 0; i < 16; ++i) acc[i] = 0.f;
    const float* wbase = Wt + ((size_t)r * 64 + warp_s * 16) * INP;

#pragma unroll 1
    for (int k4 = 0; k4 < INP / 4; ++k4) {
        float4 xv = *(const float4*)&smem[lane * XS + k4 * 4];
#pragma unroll
        for (int i = 0; i < 16; ++i) {
            float4 wv = *(const float4*)(wbase + i * INP + k4 * 4);  // wave-uniform -> s_load
            acc[i] = fmaf(xv.x, wv.x, acc[i]);
            acc[i] = fmaf(xv.y, wv.y, acc[i]);
            acc[i] = fmaf(xv.z, wv.z, acc[i]);
            acc[i] = fmaf(xv.w, wv.w, acc[i]);
        }
    }

    {
        const float* av = asrc + r * 64 + warp_s * 16;
        const float* dv = adst + r * 64 + warp_s * 16;
        float ps = 0.f, pd = 0.f;
#pragma unroll
        for (int i = 0; i < 16; ++i) { ps = fmaf(acc[i], av[i], ps); pd = fmaf(acc[i], dv[i], pd); }
        parts[warp_s * 64 + lane] = ps;
        parts[256 + warp_s * 64 + lane] = pd;
    }

    __syncthreads();
    float* outb = smem;
#pragma unroll
    for (int i = 0; i < 16; ++i) outb[lane * 65 + warp_s * 16 + i] = acc[i];
    __syncthreads();

    const int nrows = (NN - row0 < 64) ? (NN - row0) : 64;
    for (int idx = t; idx < nrows * 64; idx += 256) {
        int row = idx >> 6, c = idx & 63;
        h[((size_t)r * NN + row0 + row) * 64 + c] = outb[row * 65 + c];
    }
    if (t < nrows) {
        float s = parts[t] + parts[64 + t] + parts[128 + t] + parts[192 + t];
        float d = parts[256 + t] + parts[320 + t] + parts[384 + t] + parts[448 + t];
        als[r * NN + row0 + t] = s;
        ald[r * NN + row0 + t] = d;
    }
}

// ---------------- CSR build: deterministic counting-sort, NO global atomics ----------------

__global__ __launch_bounds__(256) void chunk_hist(
    const int* __restrict__ ei0, const int* __restrict__ ei1, const int* __restrict__ ei2,
    unsigned* __restrict__ M)
{
    __shared__ unsigned hist[NBUCK];
    const int r = blockIdx.y, bx = blockIdx.x;
    const int* ei = (r == 0) ? ei0 : ((r == 1) ? ei1 : ei2);
    const int t = threadIdx.x;
    for (int i = t; i < NBUCK; i += 256) hist[i] = 0;
    __syncthreads();
    const int e0 = bx * CHUNK_E;
    const int e1 = (e0 + CHUNK_E < EE) ? e0 + CHUNK_E : EE;
    for (int e = e0 + t; e < e1; e += 256) {
        int idx = r * NN + ei[EE + e];
        atomicAdd(&hist[idx >> 8], 1u);
    }
    __syncthreads();
    const int c = r * NCH_PER_R + bx;
    for (int i = t; i < NBUCK; i += 256) M[(size_t)i * NCH + c] = hist[i];
}

__global__ __launch_bounds__(256) void scan_block(unsigned* __restrict__ data, unsigned* __restrict__ bsum)
{
    __shared__ unsigned tsum[256];
    const int base = blockIdx.x * SCAN_CHUNK;
    const int t = threadIdx.x;
    const int i0 = base + t * 4;
    unsigned v[4];
#pragma unroll
    for (int k = 0; k < 4; ++k) v[k] = (i0 + k < MT) ? data[i0 + k] : 0u;
    unsigned run = 0;
#pragma unroll
    for (int k = 0; k < 4; ++k) { unsigned x = v[k]; v[k] = run; run += x; }
    tsum[t] = run;
    __syncthreads();
    unsigned val = run;
    for (int d = 1; d < 256; d <<= 1) {
        unsigned add = (t >= d) ? tsum[t - d] : 0u;
        __syncthreads();
        val += add;
        tsum[t] = val;
        __syncthreads();
    }
    unsigned texcl = val - run;
    if (t == 255) bsum[blockIdx.x] = val;
#pragma unroll
    for (int k = 0; k < 4; ++k)
        if (i0 + k < MT) data[i0 + k] = texcl + v[k];
}

__global__ __launch_bounds__(256) void scan_bsums(unsigned* __restrict__ bsum)
{
    __shared__ unsigned s[NSCB];
    int t = threadIdx.x;
    for (int i = t; i < NSCB; i += 256) s[i] = bsum[i];
    __syncthreads();
    if (t == 0) {
        unsigned run = 0;
        for (int i = 0; i < NSCB; ++i) { unsigned x = s[i]; s[i] = run; run += x; }
    }
    __syncthreads();
    for (int i = t; i < NSCB; i += 256) bsum[i] = s[i];
}

__global__ __launch_bounds__(256) void add_off(unsigned* __restrict__ data, const unsigned* __restrict__ bsum)
{
    int i = blockIdx.x * 256 + threadIdx.x;
    if (i >= MT) return;
    data[i] += bsum[i / SCAN_CHUNK];
}

__global__ __launch_bounds__(256) void chunk_scatter(
    const int* __restrict__ ei0, const int* __restrict__ ei1, const int* __restrict__ ei2,
    const unsigned* __restrict__ Ms, unsigned* __restrict__ packed)
{
    __shared__ unsigned cur[NBUCK];
    const int r = blockIdx.y, bx = blockIdx.x;
    const int* ei = (r == 0) ? ei0 : ((r == 1) ? ei1 : ei2);
    const int t = threadIdx.x;
    const int c = r * NCH_PER_R + bx;
    for (int i = t; i < NBUCK; i += 256) cur[i] = Ms[(size_t)i * NCH + c];
    __syncthreads();
    const int e0 = bx * CHUNK_E;
    const int e1 = (e0 + CHUNK_E < EE) ? e0 + CHUNK_E : EE;
    for (int e = e0 + t; e < e1; e += 256) {
        int src = ei[e];
        int idx = r * NN + ei[EE + e];
        unsigned pos = atomicAdd(&cur[idx >> 8], 1u);
        packed[pos] = (unsigned)src | ((unsigned)(idx & 255) << 24);
    }
}

__global__ __launch_bounds__(256) void bucket_build(
    unsigned* __restrict__ packed,        // in: pairs; out: csr_src (same buffer)
    const unsigned* __restrict__ Ms,      // scanned matrix: Ms[b*NCH] = bucket base
    unsigned* __restrict__ off)           // [NR]
{
    __shared__ unsigned sp[BCAP];
    __shared__ unsigned ssrc[BCAP];
    __shared__ unsigned scnt[BSEG];
    __shared__ unsigned scur[BSEG];
    __shared__ unsigned tsum[BSEG];
    const int b = blockIdx.x;
    const int t = threadIdx.x;
    const unsigned base = Ms[(size_t)b * NCH];
    const unsigned next = (b + 1 < NBUCK) ? Ms[(size_t)(b + 1) * NCH] : (unsigned)((size_t)RRR * EE);
    int cnt = (int)(next - base);
    if (cnt > BCAP) cnt = BCAP;
    for (int i = t; i < cnt; i += 256) sp[i] = packed[base + i];
    scnt[t] = 0;
    __syncthreads();
    for (int i = t; i < cnt; i += 256) atomicAdd(&scnt[sp[i] >> 24], 1u);
    __syncthreads();
    unsigned v = scnt[t];
    tsum[t] = v;
    __syncthreads();
    unsigned val = v;
    for (int d = 1; d < 256; d <<= 1) {
        unsigned add = (t >= d) ? tsum[t - d] : 0u;
        __syncthreads();
        val += add;
        tsum[t] = val;
        __syncthreads();
    }
    unsigned excl = val - v;
    scur[t] = excl;
    const int segs = (NR - b * BSEG < BSEG) ? (NR - b * BSEG) : BSEG;
    if (t < segs) off[b * BSEG + t] = base + excl;
    __syncthreads();
    for (int i = t; i < cnt; i += 256) {
        unsigned p = sp[i];
        unsigned pos = atomicAdd(&scur[p >> 24], 1u);
        ssrc[pos] = p & 0x00FFFFFFu;
    }
    __syncthreads();
    for (int i = t; i < cnt; i += 256) packed[base + i] = ssrc[i];
}

// ---------------- aggregation v3: single-tile fused softmax + 4-edge float4 gather ----------------
// wave per node. Fast path (all cnt<=64): one tile per relation, no online rescale;
// phase 2 processes 4 edges/iteration: lane=(sub,fc), global_load_dwordx4 (1KB/wave/instr).
template<bool L1>
__global__ __launch_bounds__(256) void aggregate3(
    const int* __restrict__ csr_src, const unsigned* __restrict__ off,
    const float* __restrict__ h,     // [R, NN, 64]
    const float* __restrict__ als, const float* __restrict__ ald,  // [R, NN]
    const float* __restrict__ bias,  // [R, 64]
    float* __restrict__ outp)        // [NN, 64]
{
    __shared__ float sbuf[4][64];    // fallback-path layout conversion only
    const int wid = threadIdx.x >> 6;
    const int node = blockIdx.x * 4 + wid;
    if (node >= NN) return;
    const int lane = threadIdx.x & 63;
    const int sub = lane >> 4;       // edge-in-group 0..3
    const int fc = lane & 15;        // float4 feature chunk 0..15

    unsigned start[RRR]; int cnt[RRR]; float aldv[RRR];
    int maxcnt = 0;
#pragma unroll
    for (int r = 0; r < RRR; ++r) {
        int idx = r * NN + node;
        unsigned s = off[idx];
        unsigned e = (idx == NR - 1) ? (unsigned)((size_t)RRR * EE) : off[idx + 1];
        start[r] = s; cnt[r] = (int)(e - s); aldv[r] = ald[idx];
        if (cnt[r] > maxcnt) maxcnt = cnt[r];
    }

    float4 total = make_float4(0.f, 0.f, 0.f, 0.f);

    if (maxcnt <= 64) {
        // ---- fused single-tile path (taken for this data: max degree << 64) ----
        int srcv[RRR]; float lr[RRR];
#pragma unroll
        for (int r = 0; r < RRR; ++r) {
            bool act = lane < cnt[r];
            int s_ = act ? csr_src[start[r] + lane] : 0;      // coalesced
            srcv[r] = s_;
            float sv = act ? (als[r * NN + s_] + aldv[r]) : -3.0e38f;  // 4B gather, L2-resident
            lr[r] = (sv > 0.f) ? sv : SLOPE * sv;
        }
        float m[RRR];
#pragma unroll
        for (int r = 0; r < RRR; ++r) m[r] = lr[r];
#pragma unroll
        for (int o = 32; o; o >>= 1) {
#pragma unroll
            for (int r = 0; r < RRR; ++r) m[r] = fmaxf(m[r], __shfl_xor(m[r], o));
        }
        float p[RRR], den[RRR];
#pragma unroll
        for (int r = 0; r < RRR; ++r) {
            p[r] = (lane < cnt[r]) ? __expf(lr[r] - m[r]) : 0.f;
            den[r] = p[r];
        }
#pragma unroll
        for (int o = 32; o; o >>= 1) {
#pragma unroll
            for (int r = 0; r < RRR; ++r) den[r] += __shfl_xor(den[r], o);
        }
#pragma unroll
        for (int r = 0; r < RRR; ++r) {
            float inv = (cnt[r] > 0) ? 1.f / den[r] : 0.f;
            const float* hr = h + (size_t)r * NN * DOUT;
            float4 acc = make_float4(0.f, 0.f, 0.f, 0.f);
            const int ng = (cnt[r] + 3) >> 2;
            for (int g = 0; g < ng; ++g) {
                int e = g * 4 + sub;                          // 4 edges in flight
                float pe = __shfl(p[r], e);                   // p=0 for e>=cnt
                int se = __shfl(srcv[r], e);
                float4 hv = *(const float4*)(hr + (size_t)se * DOUT + fc * 4);  // 1KB/wave
                acc.x = fmaf(pe, hv.x, acc.x);
                acc.y = fmaf(pe, hv.y, acc.y);
                acc.z = fmaf(pe, hv.z, acc.z);
                acc.w = fmaf(pe, hv.w, acc.w);
            }
            // reduce over the 4 sub-groups
            acc.x += __shfl_xor(acc.x, 16); acc.y += __shfl_xor(acc.y, 16);
            acc.z += __shfl_xor(acc.z, 16); acc.w += __shfl_xor(acc.w, 16);
            acc.x += __shfl_xor(acc.x, 32); acc.y += __shfl_xor(acc.y, 32);
            acc.z += __shfl_xor(acc.z, 32); acc.w += __shfl_xor(acc.w, 32);
            total.x = fmaf(acc.x, inv, total.x);
            total.y = fmaf(acc.y, inv, total.y);
            total.z = fmaf(acc.z, inv, total.z);
            total.w = fmaf(acc.w, inv, total.w);
        }
    } else {
        // ---- general fallback: online softmax, scalar broadcast (lane=feature) ----
        float totalS = 0.f;
#pragma unroll
        for (int r = 0; r < RRR; ++r) {
            if (cnt[r] <= 0) continue;
            const float* hr = h + (size_t)r * NN * DOUT;
            const float* alsr = als + (size_t)r * NN;
            float m = -3.4e38f, den = 0.f, accv = 0.f;
            for (int t0 = 0; t0 < cnt[r]; t0 += 64) {
                int j = t0 + lane;
                bool act = (j < cnt[r]);
                int src = 0;
                float lrv = -3.4e38f;
                if (act) {
                    src = csr_src[start[r] + j];
                    float sv = alsr[src] + aldv[r];
                    lrv = (sv > 0.f) ? sv : SLOPE * sv;
                }
                float mt = lrv;
#pragma unroll
                for (int o = 32; o; o >>= 1) mt = fmaxf(mt, __shfl_xor(mt, o));
                float mnew = fmaxf(m, mt);
                float scale = __expf(m - mnew);
                den *= scale; accv *= scale; m = mnew;
                float p = act ? __expf(lrv - m) : 0.f;
                float ps = p;
#pragma unroll
                for (int o = 32; o; o >>= 1) ps += __shfl_xor(ps, o);
                den += ps;
                int tcnt = cnt[r] - t0; if (tcnt > 64) tcnt = 64;
                for (int j2 = 0; j2 < tcnt; ++j2) {
                    int sj = __builtin_amdgcn_readlane(src, j2);
                    float pj = __int_as_float(__builtin_amdgcn_readlane(__float_as_int(p), j2));
                    accv = fmaf(pj, hr[(size_t)sj * DOUT + lane], accv);
                }
            }
            totalS += accv / den;
        }
        sbuf[wid][lane] = totalS;     // wave-internal layout conversion (no barrier needed)
        __builtin_amdgcn_s_waitcnt(0);
        total = *(const float4*)&sbuf[wid][fc * 4];
    }

    // ---- epilogue in float4 layout (replicated across sub) ----
    float4 b4 = make_float4(0.f, 0.f, 0.f, 0.f);
#pragma unroll
    for (int r = 0; r < RRR; ++r) {
        float4 bb = *(const float4*)(bias + r * DOUT + fc * 4);
        b4.x += bb.x; b4.y += bb.y; b4.z += bb.z; b4.w += bb.w;
    }
    float4 v;
    v.x = (total.x + b4.x) * (1.f / 3.f);
    v.y = (total.y + b4.y) * (1.f / 3.f);
    v.z = (total.z + b4.z) * (1.f / 3.f);
    v.w = (total.w + b4.w) * (1.f / 3.f);
    if (L1) {
        float ss = v.x * v.x + v.y * v.y + v.z * v.z + v.w * v.w;
#pragma unroll
        for (int o = 8; o; o >>= 1) ss += __shfl_xor(ss, o);   // sum over 16 fc in sub-group
        float di = 1.f / fmaxf(sqrtf(ss), 1e-12f);
        v.x = fmaxf(v.x * di, 0.f);
        v.y = fmaxf(v.y * di, 0.f);
        v.z = fmaxf(v.z * di, 0.f);
        v.w = fmaxf(v.w * di, 0.f);
    }
    if (sub == 0) *(float4*)(outp + (size_t)node * DOUT + fc * 4) = v;  // 256B/node, coalesced
}

// ---------------- launch ----------------
extern "C" void kernel_launch(void* const* d_in, const int* in_sizes, int n_in,
                              void* d_out, int out_size, void* d_ws, size_t ws_size,
                              hipStream_t stream) {
    const float* x   = (const float*)d_in[0];
    const int* ei0   = (const int*)d_in[1];
    const int* ei1   = (const int*)d_in[2];
    const int* ei2   = (const int*)d_in[3];
    const float* W1  = (const float*)d_in[4];
    const float* as1 = (const float*)d_in[5];
    const float* ad1 = (const float*)d_in[6];
    const float* b1  = (const float*)d_in[7];
    const float* W2  = (const float*)d_in[8];
    const float* as2 = (const float*)d_in[9];
    const float* ad2 = (const float*)d_in[10];
    const float* b2  = (const float*)d_in[11];
    float* out = (float*)d_out;

    // workspace carve-up (4B units)
    float* ws = (float*)d_ws;
    size_t off_u = 0;
    float* h        = ws + off_u; off_u += (size_t)RRR * NN * DOUT;       // 19.2M
    float* als      = ws + off_u; off_u += (size_t)RRR * NN;
    float* ald      = ws + off_u; off_u += (size_t)RRR * NN;
    unsigned* packed= (unsigned*)(ws + off_u); off_u += (size_t)RRR * EE; // 3M; becomes csr_src
    unsigned* off   = (unsigned*)(ws + off_u); off_u += NR;
    float* Wt1      = ws + off_u; off_u += (size_t)RRR * DIN * DOUT;
    float* Wt2      = ws + off_u; off_u += (size_t)RRR * DOUT * DOUT;
    float* hmid     = ws + off_u;                                          // 6.4M floats
    unsigned* M     = (unsigned*)hmid;          // overlaps hmid: MT=432k < 6.4M; dead before layer 1
    unsigned* bsum  = M + MT;

    dim3 blk(256);
    dim3 gG2((NN + 63) / 64, RRR);    // 1563 x 3
    dim3 gC(NCH_PER_R, RRR);          // 123 x 3
    int gA = NN / 4;                  // 25000

    // ---- CSR build (deterministic, no global atomics; shared by both layers) ----
    chunk_hist<<<gC, blk, 0, stream>>>(ei0, ei1, ei2, M);
    scan_block<<<NSCB, blk, 0, stream>>>(M, bsum);
    scan_bsums<<<1, blk, 0, stream>>>(bsum);
    add_off<<<(MT + 255) / 256, blk, 0, stream>>>(M, bsum);
    chunk_scatter<<<gC, blk, 0, stream>>>(ei0, ei1, ei2, M, packed);
    bucket_build<<<NBUCK, blk, 0, stream>>>(packed, M, off);
    const int* csr_src = (const int*)packed;

    transpose_W<<<6, blk, 0, stream>>>(W1, W2, Wt1, Wt2);

    // ---- layer 1 ----
    gemm_att2<DIN><<<gG2, blk, 0, stream>>>(x, Wt1, as1, ad1, h, als, ald);
    aggregate3<true><<<gA, blk, 0, stream>>>(csr_src, off, h, als, ald, b1, hmid);

    // ---- layer 2 ----
    gemm_att2<DOUT><<<gG2, blk, 0, stream>>>(hmid, Wt2, as2, ad2, h, als, ald);
    aggregate3<false><<<gA, blk, 0, stream>>>(csr_src, off, h, als, ald, b2, out);
}

// Round 7
// 434.651 us; speedup vs baseline: 4.9828x; 1.1630x over previous
//
#include <hip/hip_runtime.h>
#include <hip/hip_bf16.h>
#include <hip/hip_fp16.h>
#include <math.h>

constexpr int NN = 100000;
constexpr int EE = 1000000;
constexpr int RRR = 3;
constexpr int DIN = 128;
constexpr int DOUT = 64;
constexpr float SLOPE = 0.2f;
constexpr int NR = RRR * NN;                    // 300000 segments (relation-major)
constexpr int BSEG = 256;                       // segments per bucket
constexpr int NBUCK = (NR + BSEG - 1) / BSEG;   // 1172
constexpr int BCAP = 4096;                      // max edges/bucket (mean 2560, sigma ~51)
constexpr int CHUNK_E = 8192;                   // edges per chunk-block
constexpr int NCH_PER_R = (EE + CHUNK_E - 1) / CHUNK_E;   // 123
constexpr int NCH = RRR * NCH_PER_R;            // 369
constexpr int MT = NBUCK * NCH;                 // 432468 matrix entries
constexpr int SCAN_CHUNK = 1024;
constexpr int NSCB = (MT + SCAN_CHUNK - 1) / SCAN_CHUNK;  // 423

// ---------------- W pre-transpose: Wt[r][c][k] = W[r][k][c] ----------------
__global__ __launch_bounds__(256) void transpose_W(
    const float* __restrict__ W1, const float* __restrict__ W2,
    float* __restrict__ Wt1, float* __restrict__ Wt2)
{
    int m = blockIdx.x;     // 0..2: W1 (K=128), 3..5: W2 (K=64)
    int t = threadIdx.x;
    if (m < 3) {
        const float* src = W1 + (size_t)m * DIN * DOUT;
        float* dst = Wt1 + (size_t)m * DIN * DOUT;
        for (int i = t; i < DIN * DOUT; i += 256) {
            int k = i >> 6, c = i & 63;
            dst[c * DIN + k] = src[i];
        }
    } else {
        const float* src = W2 + (size_t)(m - 3) * DOUT * DOUT;
        float* dst = Wt2 + (size_t)(m - 3) * DOUT * DOUT;
        for (int i = t; i < DOUT * DOUT; i += 256) {
            int k = i >> 6, c = i & 63;
            dst[c * DOUT + k] = src[i];
        }
    }
}

// ---------------- GEMM + attention logits: lane=row, scalar W loads; h stored fp16 ----------------
template<int INP>
__global__ __launch_bounds__(256) void gemm_att2(
    const float* __restrict__ x,     // [NN, INP]
    const float* __restrict__ Wt,    // [R, 64, INP] (k-contiguous per col)
    const float* __restrict__ asrc,  // [R, 64]
    const float* __restrict__ adst,  // [R, 64]
    __half* __restrict__ h,          // [R, NN, 64] fp16
    float* __restrict__ als,         // [R, NN]
    float* __restrict__ ald)         // [R, NN]
{
    constexpr int XS = INP + 1;                 // odd word stride -> conflict-free b128
    constexpr int KLOG = (INP == 128) ? 5 : 4;  // log2(INP/4)
    __shared__ float smem[64 * XS];             // xs during k-loop; out[64][65] after
    __shared__ float parts[512];                // als/ald partials: [2][4][64]
    const int t = threadIdx.x;
    const int lane = t & 63;
    const int warp_s = __builtin_amdgcn_readfirstlane(t >> 6);
    const int r = blockIdx.y;
    const int row0 = blockIdx.x * 64;

    for (int idx = t; idx < 64 * (INP / 4); idx += 256) {
        int row = idx >> KLOG, kk = idx & ((INP / 4) - 1);
        int grow = row0 + row; if (grow >= NN) grow = NN - 1;
        *(float4*)&smem[row * XS + kk * 4] = *(const float4*)(x + (size_t)grow * INP + kk * 4);
    }
    __syncthreads();

    float acc[16];
#pragma unroll
    for (int i = 0; i < 16; ++i) acc[i] = 0.f;
    const float* wbase = Wt + ((size_t)r * 64 + warp_s * 16) * INP;

#pragma unroll 1
    for (int k4 = 0; k4 < INP / 4; ++k4) {
        float4 xv = *(const float4*)&smem[lane * XS + k4 * 4];
#pragma unroll
        for (int i = 0; i < 16; ++i) {
            float4 wv = *(const float4*)(wbase + i * INP + k4 * 4);  // wave-uniform -> s_load
            acc[i] = fmaf(xv.x, wv.x, acc[i]);
            acc[i] = fmaf(xv.y, wv.y, acc[i]);
            acc[i] = fmaf(xv.z, wv.z, acc[i]);
            acc[i] = fmaf(xv.w, wv.w, acc[i]);
        }
    }

    {
        const float* av = asrc + r * 64 + warp_s * 16;
        const float* dv = adst + r * 64 + warp_s * 16;
        float ps = 0.f, pd = 0.f;
#pragma unroll
        for (int i = 0; i < 16; ++i) { ps = fmaf(acc[i], av[i], ps); pd = fmaf(acc[i], dv[i], pd); }
        parts[warp_s * 64 + lane] = ps;
        parts[256 + warp_s * 64 + lane] = pd;
    }

    __syncthreads();
    float* outb = smem;
#pragma unroll
    for (int i = 0; i < 16; ++i) outb[lane * 65 + warp_s * 16 + i] = acc[i];
    __syncthreads();

    const int nrows = (NN - row0 < 64) ? (NN - row0) : 64;
    __half2* h2 = (__half2*)(h + ((size_t)r * NN + row0) * 64);
    for (int idx = t; idx < nrows * 32; idx += 256) {
        int row = idx >> 5, cc = idx & 31;
        float f0 = outb[row * 65 + cc * 2];
        float f1 = outb[row * 65 + cc * 2 + 1];
        h2[row * 32 + cc] = __floats2half2_rn(f0, f1);    // coalesced 4B stores
    }
    if (t < nrows) {
        float s = parts[t] + parts[64 + t] + parts[128 + t] + parts[192 + t];
        float d = parts[256 + t] + parts[320 + t] + parts[384 + t] + parts[448 + t];
        als[r * NN + row0 + t] = s;
        ald[r * NN + row0 + t] = d;
    }
}

// ---------------- CSR build: deterministic counting-sort, NO global atomics ----------------

__global__ __launch_bounds__(256) void chunk_hist(
    const int* __restrict__ ei0, const int* __restrict__ ei1, const int* __restrict__ ei2,
    unsigned* __restrict__ M)
{
    __shared__ unsigned hist[NBUCK];
    const int r = blockIdx.y, bx = blockIdx.x;
    const int* ei = (r == 0) ? ei0 : ((r == 1) ? ei1 : ei2);
    const int t = threadIdx.x;
    for (int i = t; i < NBUCK; i += 256) hist[i] = 0;
    __syncthreads();
    const int e0 = bx * CHUNK_E;
    const int e1 = (e0 + CHUNK_E < EE) ? e0 + CHUNK_E : EE;
    for (int e = e0 + t; e < e1; e += 256) {
        int idx = r * NN + ei[EE + e];
        atomicAdd(&hist[idx >> 8], 1u);
    }
    __syncthreads();
    const int c = r * NCH_PER_R + bx;
    for (int i = t; i < NBUCK; i += 256) M[(size_t)i * NCH + c] = hist[i];
}

__global__ __launch_bounds__(256) void scan_block(unsigned* __restrict__ data, unsigned* __restrict__ bsum)
{
    __shared__ unsigned tsum[256];
    const int base = blockIdx.x * SCAN_CHUNK;
    const int t = threadIdx.x;
    const int i0 = base + t * 4;
    unsigned v[4];
#pragma unroll
    for (int k = 0; k < 4; ++k) v[k] = (i0 + k < MT) ? data[i0 + k] : 0u;
    unsigned run = 0;
#pragma unroll
    for (int k = 0; k < 4; ++k) { unsigned x = v[k]; v[k] = run; run += x; }
    tsum[t] = run;
    __syncthreads();
    unsigned val = run;
    for (int d = 1; d < 256; d <<= 1) {
        unsigned add = (t >= d) ? tsum[t - d] : 0u;
        __syncthreads();
        val += add;
        tsum[t] = val;
        __syncthreads();
    }
    unsigned texcl = val - run;
    if (t == 255) bsum[blockIdx.x] = val;
#pragma unroll
    for (int k = 0; k < 4; ++k)
        if (i0 + k < MT) data[i0 + k] = texcl + v[k];
}

__global__ __launch_bounds__(256) void scan_bsums(unsigned* __restrict__ bsum)
{
    __shared__ unsigned s[NSCB];
    int t = threadIdx.x;
    for (int i = t; i < NSCB; i += 256) s[i] = bsum[i];
    __syncthreads();
    if (t == 0) {
        unsigned run = 0;
        for (int i = 0; i < NSCB; ++i) { unsigned x = s[i]; s[i] = run; run += x; }
    }
    __syncthreads();
    for (int i = t; i < NSCB; i += 256) bsum[i] = s[i];
}

__global__ __launch_bounds__(256) void add_off(unsigned* __restrict__ data, const unsigned* __restrict__ bsum)
{
    int i = blockIdx.x * 256 + threadIdx.x;
    if (i >= MT) return;
    data[i] += bsum[i / SCAN_CHUNK];
}

__global__ __launch_bounds__(256) void chunk_scatter(
    const int* __restrict__ ei0, const int* __restrict__ ei1, const int* __restrict__ ei2,
    const unsigned* __restrict__ Ms, unsigned* __restrict__ packed)
{
    __shared__ unsigned cur[NBUCK];
    const int r = blockIdx.y, bx = blockIdx.x;
    const int* ei = (r == 0) ? ei0 : ((r == 1) ? ei1 : ei2);
    const int t = threadIdx.x;
    const int c = r * NCH_PER_R + bx;
    for (int i = t; i < NBUCK; i += 256) cur[i] = Ms[(size_t)i * NCH + c];
    __syncthreads();
    const int e0 = bx * CHUNK_E;
    const int e1 = (e0 + CHUNK_E < EE) ? e0 + CHUNK_E : EE;
    for (int e = e0 + t; e < e1; e += 256) {
        int src = ei[e];
        int idx = r * NN + ei[EE + e];
        unsigned pos = atomicAdd(&cur[idx >> 8], 1u);
        packed[pos] = (unsigned)src | ((unsigned)(idx & 255) << 24);
    }
}

__global__ __launch_bounds__(256) void bucket_build(
    unsigned* __restrict__ packed,        // in: pairs; out: csr_src (same buffer)
    const unsigned* __restrict__ Ms,      // scanned matrix: Ms[b*NCH] = bucket base
    unsigned* __restrict__ off)           // [NR]
{
    __shared__ unsigned sp[BCAP];
    __shared__ unsigned ssrc[BCAP];
    __shared__ unsigned scnt[BSEG];
    __shared__ unsigned scur[BSEG];
    __shared__ unsigned tsum[BSEG];
    const int b = blockIdx.x;
    const int t = threadIdx.x;
    const unsigned base = Ms[(size_t)b * NCH];
    const unsigned next = (b + 1 < NBUCK) ? Ms[(size_t)(b + 1) * NCH] : (unsigned)((size_t)RRR * EE);
    int cnt = (int)(next - base);
    if (cnt > BCAP) cnt = BCAP;
    for (int i = t; i < cnt; i += 256) sp[i] = packed[base + i];
    scnt[t] = 0;
    __syncthreads();
    for (int i = t; i < cnt; i += 256) atomicAdd(&scnt[sp[i] >> 24], 1u);
    __syncthreads();
    unsigned v = scnt[t];
    tsum[t] = v;
    __syncthreads();
    unsigned val = v;
    for (int d = 1; d < 256; d <<= 1) {
        unsigned add = (t >= d) ? tsum[t - d] : 0u;
        __syncthreads();
        val += add;
        tsum[t] = val;
        __syncthreads();
    }
    unsigned excl = val - v;
    scur[t] = excl;
    const int segs = (NR - b * BSEG < BSEG) ? (NR - b * BSEG) : BSEG;
    if (t < segs) off[b * BSEG + t] = base + excl;
    __syncthreads();
    for (int i = t; i < cnt; i += 256) {
        unsigned p = sp[i];
        unsigned pos = atomicAdd(&scur[p >> 24], 1u);
        ssrc[pos] = p & 0x00FFFFFFu;
    }
    __syncthreads();
    for (int i = t; i < cnt; i += 256) packed[base + i] = ssrc[i];
}

// ---------------- aggregation v4: single-tile softmax + fp16 8-edge-unrolled gather ----------------
// wave per node; lane=(sub,fc). Phase 2: 2 groups (8 edges, 2 dwordx2 loads) in flight per iter.
template<bool L1>
__global__ __launch_bounds__(256) void aggregate4(
    const int* __restrict__ csr_src, const unsigned* __restrict__ off,
    const __half* __restrict__ h,    // [R, NN, 64] fp16
    const float* __restrict__ als, const float* __restrict__ ald,  // [R, NN]
    const float* __restrict__ bias,  // [R, 64]
    float* __restrict__ outp)        // [NN, 64]
{
    __shared__ float sbuf[4][64];    // fallback-path layout conversion only
    const int wid = threadIdx.x >> 6;
    const int node = blockIdx.x * 4 + wid;
    if (node >= NN) return;
    const int lane = threadIdx.x & 63;
    const int sub = lane >> 4;       // edge-in-group 0..3
    const int fc = lane & 15;        // feature chunk 0..15 (4 floats each)

    unsigned start[RRR]; int cnt[RRR]; float aldv[RRR];
    int maxcnt = 0;
#pragma unroll
    for (int r = 0; r < RRR; ++r) {
        int idx = r * NN + node;
        unsigned s = off[idx];
        unsigned e = (idx == NR - 1) ? (unsigned)((size_t)RRR * EE) : off[idx + 1];
        start[r] = s; cnt[r] = (int)(e - s); aldv[r] = ald[idx];
        if (cnt[r] > maxcnt) maxcnt = cnt[r];
    }

    float4 total = make_float4(0.f, 0.f, 0.f, 0.f);

    if (maxcnt <= 64) {
        // ---- fused single-tile path (max degree << 64 for this data) ----
        int srcv[RRR]; float lr[RRR];
#pragma unroll
        for (int r = 0; r < RRR; ++r) {
            bool act = lane < cnt[r];
            int s_ = act ? csr_src[start[r] + lane] : 0;      // coalesced
            srcv[r] = s_;
            float sv = act ? (als[r * NN + s_] + aldv[r]) : -3.0e38f;  // 4B gather, L2-resident
            lr[r] = (sv > 0.f) ? sv : SLOPE * sv;
        }
        float m[RRR];
#pragma unroll
        for (int r = 0; r < RRR; ++r) m[r] = lr[r];
#pragma unroll
        for (int o = 32; o; o >>= 1) {
#pragma unroll
            for (int r = 0; r < RRR; ++r) m[r] = fmaxf(m[r], __shfl_xor(m[r], o));
        }
        float p[RRR], den[RRR];
#pragma unroll
        for (int r = 0; r < RRR; ++r) {
            p[r] = (lane < cnt[r]) ? __expf(lr[r] - m[r]) : 0.f;
            den[r] = p[r];
        }
#pragma unroll
        for (int o = 32; o; o >>= 1) {
#pragma unroll
            for (int r = 0; r < RRR; ++r) den[r] += __shfl_xor(den[r], o);
        }
#pragma unroll
        for (int r = 0; r < RRR; ++r) {
            float inv = (cnt[r] > 0) ? 1.f / den[r] : 0.f;
            const __half* hr = h + (size_t)r * NN * DOUT;
            float4 acc = make_float4(0.f, 0.f, 0.f, 0.f);
            const int ng = (cnt[r] + 3) >> 2;
            for (int g = 0; g < ng; g += 2) {
                // two groups (8 edges) in flight; eb <= 63 for all cnt <= 64 (p=0 past cnt)
                int ea = g * 4 + sub, eb = ea + 4;
                float pa = __shfl(p[r], ea);
                int sa = __shfl(srcv[r], ea);
                float pb = __shfl(p[r], eb);
                int sb = __shfl(srcv[r], eb);
                uint2 ra = *(const uint2*)(hr + (size_t)sa * DOUT + fc * 4);  // 8B = 4 halves
                uint2 rb = *(const uint2*)(hr + (size_t)sb * DOUT + fc * 4);
                float2 fa01 = __half22float2(*(const __half2*)&ra.x);
                float2 fa23 = __half22float2(*(const __half2*)&ra.y);
                acc.x = fmaf(pa, fa01.x, acc.x);
                acc.y = fmaf(pa, fa01.y, acc.y);
                acc.z = fmaf(pa, fa23.x, acc.z);
                acc.w = fmaf(pa, fa23.y, acc.w);
                float2 fb01 = __half22float2(*(const __half2*)&rb.x);
                float2 fb23 = __half22float2(*(const __half2*)&rb.y);
                acc.x = fmaf(pb, fb01.x, acc.x);
                acc.y = fmaf(pb, fb01.y, acc.y);
                acc.z = fmaf(pb, fb23.x, acc.z);
                acc.w = fmaf(pb, fb23.y, acc.w);
            }
            // reduce over the 4 sub-groups
            acc.x += __shfl_xor(acc.x, 16); acc.y += __shfl_xor(acc.y, 16);
            acc.z += __shfl_xor(acc.z, 16); acc.w += __shfl_xor(acc.w, 16);
            acc.x += __shfl_xor(acc.x, 32); acc.y += __shfl_xor(acc.y, 32);
            acc.z += __shfl_xor(acc.z, 32); acc.w += __shfl_xor(acc.w, 32);
            total.x = fmaf(acc.x, inv, total.x);
            total.y = fmaf(acc.y, inv, total.y);
            total.z = fmaf(acc.z, inv, total.z);
            total.w = fmaf(acc.w, inv, total.w);
        }
    } else {
        // ---- general fallback: online softmax, scalar broadcast (lane=feature) ----
        float totalS = 0.f;
#pragma unroll
        for (int r = 0; r < RRR; ++r) {
            if (cnt[r] <= 0) continue;
            const __half* hr = h + (size_t)r * NN * DOUT;
            const float* alsr = als + (size_t)r * NN;
            float m = -3.4e38f, den = 0.f, accv = 0.f;
            for (int t0 = 0; t0 < cnt[r]; t0 += 64) {
                int j = t0 + lane;
                bool act = (j < cnt[r]);
                int src = 0;
                float lrv = -3.4e38f;
                if (act) {
                    src = csr_src[start[r] + j];
                    float sv = alsr[src] + aldv[r];
                    lrv = (sv > 0.f) ? sv : SLOPE * sv;
                }
                float mt = lrv;
#pragma unroll
                for (int o = 32; o; o >>= 1) mt = fmaxf(mt, __shfl_xor(mt, o));
                float mnew = fmaxf(m, mt);
                float scale = __expf(m - mnew);
                den *= scale; accv *= scale; m = mnew;
                float p = act ? __expf(lrv - m) : 0.f;
                float ps = p;
#pragma unroll
                for (int o = 32; o; o >>= 1) ps += __shfl_xor(ps, o);
                den += ps;
                int tcnt = cnt[r] - t0; if (tcnt > 64) tcnt = 64;
                for (int j2 = 0; j2 < tcnt; ++j2) {
                    int sj = __builtin_amdgcn_readlane(src, j2);
                    float pj = __int_as_float(__builtin_amdgcn_readlane(__float_as_int(p), j2));
                    accv = fmaf(pj, __half2float(hr[(size_t)sj * DOUT + lane]), accv);
                }
            }
            totalS += accv / den;
        }
        sbuf[wid][lane] = totalS;     // wave-internal layout conversion
        __builtin_amdgcn_s_waitcnt(0);
        total = *(const float4*)&sbuf[wid][fc * 4];
    }

    // ---- epilogue in float4 layout (replicated across sub) ----
    float4 b4 = make_float4(0.f, 0.f, 0.f, 0.f);
#pragma unroll
    for (int r = 0; r < RRR; ++r) {
        float4 bb = *(const float4*)(bias + r * DOUT + fc * 4);
        b4.x += bb.x; b4.y += bb.y; b4.z += bb.z; b4.w += bb.w;
    }
    float4 v;
    v.x = (total.x + b4.x) * (1.f / 3.f);
    v.y = (total.y + b4.y) * (1.f / 3.f);
    v.z = (total.z + b4.z) * (1.f / 3.f);
    v.w = (total.w + b4.w) * (1.f / 3.f);
    if (L1) {
        float ss = v.x * v.x + v.y * v.y + v.z * v.z + v.w * v.w;
#pragma unroll
        for (int o = 8; o; o >>= 1) ss += __shfl_xor(ss, o);   // sum over 16 fc in sub-group
        float di = 1.f / fmaxf(sqrtf(ss), 1e-12f);
        v.x = fmaxf(v.x * di, 0.f);
        v.y = fmaxf(v.y * di, 0.f);
        v.z = fmaxf(v.z * di, 0.f);
        v.w = fmaxf(v.w * di, 0.f);
    }
    if (sub == 0) *(float4*)(outp + (size_t)node * DOUT + fc * 4) = v;  // 256B/node, coalesced
}

// ---------------- launch ----------------
extern "C" void kernel_launch(void* const* d_in, const int* in_sizes, int n_in,
                              void* d_out, int out_size, void* d_ws, size_t ws_size,
                              hipStream_t stream) {
    const float* x   = (const float*)d_in[0];
    const int* ei0   = (const int*)d_in[1];
    const int* ei1   = (const int*)d_in[2];
    const int* ei2   = (const int*)d_in[3];
    const float* W1  = (const float*)d_in[4];
    const float* as1 = (const float*)d_in[5];
    const float* ad1 = (const float*)d_in[6];
    const float* b1  = (const float*)d_in[7];
    const float* W2  = (const float*)d_in[8];
    const float* as2 = (const float*)d_in[9];
    const float* ad2 = (const float*)d_in[10];
    const float* b2  = (const float*)d_in[11];
    float* out = (float*)d_out;

    // workspace carve-up (4B units)
    float* ws = (float*)d_ws;
    size_t off_u = 0;
    __half* h       = (__half*)(ws + off_u); off_u += (size_t)RRR * NN * DOUT / 2;  // fp16: 9.6M floats
    float* als      = ws + off_u; off_u += (size_t)RRR * NN;
    float* ald      = ws + off_u; off_u += (size_t)RRR * NN;
    unsigned* packed= (unsigned*)(ws + off_u); off_u += (size_t)RRR * EE; // 3M; becomes csr_src
    unsigned* off   = (unsigned*)(ws + off_u); off_u += NR;
    float* Wt1      = ws + off_u; off_u += (size_t)RRR * DIN * DOUT;
    float* Wt2      = ws + off_u; off_u += (size_t)RRR * DOUT * DOUT;
    float* hmid     = ws + off_u;                                          // 6.4M floats
    unsigned* M     = (unsigned*)hmid;          // overlaps hmid: MT=432k < 6.4M; dead before layer 1
    unsigned* bsum  = M + MT;

    dim3 blk(256);
    dim3 gG2((NN + 63) / 64, RRR);    // 1563 x 3
    dim3 gC(NCH_PER_R, RRR);          // 123 x 3
    int gA = NN / 4;                  // 25000

    // ---- CSR build (deterministic, no global atomics; shared by both layers) ----
    chunk_hist<<<gC, blk, 0, stream>>>(ei0, ei1, ei2, M);
    scan_block<<<NSCB, blk, 0, stream>>>(M, bsum);
    scan_bsums<<<1, blk, 0, stream>>>(bsum);
    add_off<<<(MT + 255) / 256, blk, 0, stream>>>(M, bsum);
    chunk_scatter<<<gC, blk, 0, stream>>>(ei0, ei1, ei2, M, packed);
    bucket_build<<<NBUCK, blk, 0, stream>>>(packed, M, off);
    const int* csr_src = (const int*)packed;

    transpose_W<<<6, blk, 0, stream>>>(W1, W2, Wt1, Wt2);

    // ---- layer 1 ----
    gemm_att2<DIN><<<gG2, blk, 0, stream>>>(x, Wt1, as1, ad1, h, als, ald);
    aggregate4<true><<<gA, blk, 0, stream>>>(csr_src, off, h, als, ald, b1, hmid);

    // ---- layer 2 ----
    gemm_att2<DOUT><<<gG2, blk, 0, stream>>>(hmid, Wt2, as2, ad2, h, als, ald);
    aggregate4<false><<<gA, blk, 0, stream>>>(csr_src, off, h, als, ald, b2, out);
}